// Round 1
// baseline (11.758 us; speedup 1.0000x reference)
//
#include <hip/hip_runtime.h>

// SplineNetwork: cubic-convolution interpolation on a regular 128x128 grid.
// Support radius 2h = 2/128 < grid spacing 2/127, so only the 2x2 cell
// corners around each query can contribute; equivalent to the reference's
// 9-NN + cubic_conv sum.

#define NGRID 128

__global__ __launch_bounds__(256)
void SplineNetwork_kernel(const float* __restrict__ x,
                          const float* __restrict__ w,
                          const float* __restrict__ cp,
                          float* __restrict__ out, int batch) {
    int b = blockIdx.x * blockDim.x + threadIdx.x;
    if (b >= batch) return;

    float qx = x[2 * b];
    float qy = x[2 * b + 1];

    // cell index: t[i] = -1 + i*(2/127)  =>  u = (x+1)*63.5
    float u = (qx + 1.0f) * 63.5f;
    float v = (qy + 1.0f) * 63.5f;
    int i0 = (int)floorf(u);
    int j0 = (int)floorf(v);
    i0 = max(0, min(NGRID - 2, i0));
    j0 = max(0, min(NGRID - 2, j0));

    float acc = 0.0f;
#pragma unroll
    for (int di = 0; di < 2; ++di) {
#pragma unroll
        for (int dj = 0; dj < 2; ++dj) {
            int idx = (i0 + di) * NGRID + (j0 + dj);
            // load actual control point coords so exact-hit (dist==0) cases
            // match the reference's strict a>0 mask bit-for-bit
            float cx = cp[2 * idx];
            float cy = cp[2 * idx + 1];
            float dx = qx - cx;
            float dy = qy - cy;
            float a = sqrtf(dx * dx + dy * dy) * 128.0f;  // norm / h, h = 1/128
            float r = 0.0f;
            if (a > 0.0f && a < 1.0f) {
                r = 1.5f * a * a * a - 2.5f * a * a + 1.0f;
            } else if (a > 1.0f && a < 2.0f) {
                r = -0.5f * a * a * a + 2.5f * a * a - 4.0f * a + 2.0f;
            }
            acc += w[idx] * r;
        }
    }
    out[b] = acc;
}

extern "C" void kernel_launch(void* const* d_in, const int* in_sizes, int n_in,
                              void* d_out, int out_size, void* d_ws, size_t ws_size,
                              hipStream_t stream) {
    const float* x  = (const float*)d_in[0];  // (batch, 2)
    const float* w  = (const float*)d_in[1];  // (N*N,)
    const float* cp = (const float*)d_in[2];  // (N*N, 2)
    float* out = (float*)d_out;

    int batch = in_sizes[0] / 2;
    int block = 256;
    int grid = (batch + block - 1) / block;
    SplineNetwork_kernel<<<grid, block, 0, stream>>>(x, w, cp, out, batch);
}